// Round 4
// baseline (262.243 us; speedup 1.0000x reference)
//
#include <hip/hip_runtime.h>
#include <hip/hip_bf16.h>

// Problem constants (from reference setup_inputs)
#define NB   2
#define LQN  4000
#define CC   256     // C
#define DD   32      // C/M
#define LIN  5440    // sum of H*W over levels

// C = A @ [W1 | W2] + [b1 | b2]; A: (rows,256) f32 row-major, W: (256,256) f32 row-major.
// grid.x = rows/64 row tiles; grid.y = total 64-col tiles (first colTiles1 -> W1/C1).
__global__ __launch_bounds__(256) void gemm64(
    const float* __restrict__ A,
    const float* __restrict__ W1, const float* __restrict__ bias1, float* __restrict__ C1,
    const float* __restrict__ W2, const float* __restrict__ bias2, float* __restrict__ C2,
    int colTiles1)
{
    const int K = 256, N = 256;
    const int mt = blockIdx.x;
    const int ctg = blockIdx.y;
    const float* W; const float* bb; float* C; int ct;
    if (ctg < colTiles1) { W = W1; bb = bias1; C = C1; ct = ctg; }
    else                 { W = W2; bb = bias2; C = C2; ct = ctg - colTiles1; }
    const int row0 = mt * 64, col0 = ct * 64;
    const int tid = threadIdx.x;
    const int tx = tid & 15, ty = tid >> 4;

    __shared__ float sA[16][68];   // [k][m]
    __shared__ float sB[16][68];   // [k][n]

    float acc[4][4] = {};

    const int ar = tid >> 2;        // A-load row 0..63
    const int ak = (tid & 3) * 4;   // A-load k quad
    const int bk = tid >> 4;        // B-load k 0..15
    const int bn = (tid & 15) * 4;  // B-load col quad

    for (int kk = 0; kk < K; kk += 16) {
        float4 av = *(const float4*)&A[(row0 + ar) * K + kk + ak];
        float4 bv = *(const float4*)&W[(kk + bk) * N + col0 + bn];
        __syncthreads();             // previous iteration's compute done
        sA[ak + 0][ar] = av.x;
        sA[ak + 1][ar] = av.y;
        sA[ak + 2][ar] = av.z;
        sA[ak + 3][ar] = av.w;
        *(float4*)&sB[bk][bn] = bv;
        __syncthreads();
        #pragma unroll
        for (int k = 0; k < 16; ++k) {
            float4 a4 = *(const float4*)&sA[k][ty * 4];
            float4 b4 = *(const float4*)&sB[k][tx * 4];
            float ax[4] = {a4.x, a4.y, a4.z, a4.w};
            float bx[4] = {b4.x, b4.y, b4.z, b4.w};
            #pragma unroll
            for (int i = 0; i < 4; ++i)
                #pragma unroll
                for (int j = 0; j < 4; ++j)
                    acc[i][j] = fmaf(ax[i], bx[j], acc[i][j]);
        }
    }

    #pragma unroll
    for (int i = 0; i < 4; ++i) {
        const int r = row0 + ty * 4 + i;
        #pragma unroll
        for (int j = 0; j < 4; ++j) {
            const int c = col0 + tx * 4 + j;
            C[r * N + c] = acc[i][j] + bb[c];
        }
    }
}

// Fused bilinear sampling + key-aware attention.
// Block = one (n, qi); thread = (m = tid/32, d = tid%32).
__global__ __launch_bounds__(256) void sample_attn(
    const float* __restrict__ qproj,   // [NB][LQN][256]  (m*32+d)
    const float* __restrict__ offp,    // [NB][LQN][256]  (m*32+l*8+p*2+c), bias added
    const float* __restrict__ refp,    // [NB][LQN][4][2]
    const float* __restrict__ value,   // [NB][LIN][256]
    const float* __restrict__ keyf,    // [NB][LIN][256]
    float* __restrict__ outmid)        // [NB][LQN][256]
{
    const int bx = blockIdx.x;
    const int n = bx / LQN;
    const int qi = bx - n * LQN;
    const int tid = threadIdx.x;
    const int m = tid >> 5;
    const int d = tid & 31;

    __shared__ float s_off[256];
    __shared__ float s_ref[8];

    const int baseq = (n * LQN + qi) * CC;
    s_off[tid] = offp[baseq + tid];
    if (tid < 8) s_ref[tid] = refp[(n * LQN + qi) * 8 + tid];
    __syncthreads();

    const float qv = qproj[baseq + m * DD + d];
    const int vbase = n * LIN * CC + m * DD + d;

    float logit[16], vs[16];

    int pt = 0;
    #pragma unroll
    for (int l = 0; l < 4; ++l) {
        const int HW = (l == 0) ? 64 : (l == 1) ? 32 : (l == 2) ? 16 : 8;   // W == H
        const int st = (l == 0) ? 0 : (l == 1) ? 4096 : (l == 2) ? 5120 : 5376;
        const float inv = 1.0f / (float)HW;
        const float rx = s_ref[l * 2 + 0];
        const float ry = s_ref[l * 2 + 1];
        const int lbase = vbase + st * CC;
        #pragma unroll
        for (int p = 0; p < 4; ++p, ++pt) {
            const int oi = m * 32 + l * 8 + p * 2;
            float x = (rx + s_off[oi + 0] * inv) * (float)HW - 0.5f;
            float y = (ry + s_off[oi + 1] * inv) * (float)HW - 0.5f;
            float x0f = floorf(x), y0f = floorf(y);
            float tx = x - x0f, ty = y - y0f;
            int x0 = (int)x0f, y0 = (int)y0f;
            int x1 = x0 + 1, y1 = y0 + 1;
            float fx0 = (x0 >= 0 && x0 < HW) ? (1.0f - tx) : 0.0f;
            float fx1 = (x1 >= 0 && x1 < HW) ? tx : 0.0f;
            float fy0 = (y0 >= 0 && y0 < HW) ? (1.0f - ty) : 0.0f;
            float fy1 = (y1 >= 0 && y1 < HW) ? ty : 0.0f;
            int xc0 = min(max(x0, 0), HW - 1), xc1 = min(max(x1, 0), HW - 1);
            int yc0 = min(max(y0, 0), HW - 1), yc1 = min(max(y1, 0), HW - 1);
            int i00 = lbase + (yc0 * HW + xc0) * CC;
            int i10 = lbase + (yc0 * HW + xc1) * CC;
            int i01 = lbase + (yc1 * HW + xc0) * CC;
            int i11 = lbase + (yc1 * HW + xc1) * CC;
            float w00 = fx0 * fy0, w10 = fx1 * fy0, w01 = fx0 * fy1, w11 = fx1 * fy1;
            float ks = w00 * keyf[i00] + w10 * keyf[i10] + w01 * keyf[i01] + w11 * keyf[i11];
            float vv = w00 * value[i00] + w10 * value[i10] + w01 * value[i01] + w11 * value[i11];
            float part = qv * ks;
            #pragma unroll
            for (int o = 16; o; o >>= 1) part += __shfl_xor(part, o, 32);
            logit[pt] = part * 0.17677669529663687f;  // 1/sqrt(32)
            vs[pt] = vv;
        }
    }

    float mx = logit[0];
    #pragma unroll
    for (int i = 1; i < 16; ++i) mx = fmaxf(mx, logit[i]);
    float Z = 0.0f, acc = 0.0f;
    #pragma unroll
    for (int i = 0; i < 16; ++i) {
        float e = __expf(logit[i] - mx);
        Z += e;
        acc = fmaf(e, vs[i], acc);
    }
    outmid[baseq + m * DD + d] = acc / Z;
}

extern "C" void kernel_launch(void* const* d_in, const int* in_sizes, int n_in,
                              void* d_out, int out_size, void* d_ws, size_t ws_size,
                              hipStream_t stream) {
    const float* query = (const float*)d_in[0];
    const float* refp  = (const float*)d_in[1];
    const float* xflat = (const float*)d_in[2];
    // d_in[3] spatial shapes, d_in[4] level starts: compile-time constants
    const float* Wv   = (const float*)d_in[5];
    const float* bv   = (const float*)d_in[6];
    const float* Wk   = (const float*)d_in[7];
    const float* bk   = (const float*)d_in[8];
    const float* Wq   = (const float*)d_in[9];
    const float* bq   = (const float*)d_in[10];
    const float* Woff = (const float*)d_in[11];
    const float* boff = (const float*)d_in[12];
    const float* Wout = (const float*)d_in[13];
    const float* bout = (const float*)d_in[14];

    char* ws = (char*)d_ws;
    float* value  = (float*)ws; ws += (size_t)NB * LIN * CC * sizeof(float);
    float* keyf   = (float*)ws; ws += (size_t)NB * LIN * CC * sizeof(float);
    float* qproj  = (float*)ws; ws += (size_t)NB * LQN * CC * sizeof(float);
    float* offp   = (float*)ws; ws += (size_t)NB * LQN * CC * sizeof(float);
    float* outmid = (float*)ws; ws += (size_t)NB * LQN * CC * sizeof(float);

    dim3 blk(256);

    // value = xflat@Wv+bv ; keyf = xflat@Wk+bk   (10880 rows)
    dim3 g1((NB * LIN) / 64, 8);
    gemm64<<<g1, blk, 0, stream>>>(xflat, Wv, bv, value, Wk, bk, keyf, 4);

    // qproj = query@Wq+bq ; offp = query@Woff+boff   (8000 rows)
    dim3 g2((NB * LQN) / 64, 8);
    gemm64<<<g2, blk, 0, stream>>>(query, Wq, bq, qproj, Woff, boff, offp, 4);

    // fused deformable sampling + key-aware attention
    sample_attn<<<dim3(NB * LQN), blk, 0, stream>>>(qproj, offp, refp, value, keyf, outmid);

    // out = outmid@Wout+bout -> f32 d_out (reference output dtype is float32)
    dim3 g3((NB * LQN) / 64, 4);
    gemm64<<<g3, blk, 0, stream>>>(outmid, Wout, bout, (float*)d_out,
                                   nullptr, nullptr, nullptr, 4);
}

// Round 5
// 241.189 us; speedup vs baseline: 1.0873x; 1.0873x over previous
//
#include <hip/hip_runtime.h>

// Problem constants (from reference setup_inputs)
#define NB   2
#define LQN  4000
#define CC   256     // C
#define LIN  5440    // sum of H*W over levels

// ---------------------------------------------------------------------------
// GEMM: C = A @ W + b, K=N=256, for up to two A-problems, each with a 512-col
// concatenated weight pair [Wa|Wb] / [Wc|Wd]. BM in {128,64}, BN=128, BK=16,
// 256 threads, per-thread microtile (BM/16) rows x 8 cols in split quads
// (cols tx*4 and tx*4+64; rows ty*4 and ty*4+64) -> 2-way-max LDS aliasing.
// ---------------------------------------------------------------------------
template<int BM>
__global__ __launch_bounds__(256) void gemm_f32(
    const float* __restrict__ A1, int rows1,
    const float* __restrict__ Wa, const float* __restrict__ ba, float* __restrict__ Ca,
    const float* __restrict__ Wb, const float* __restrict__ bb_, float* __restrict__ Cb,
    const float* __restrict__ A2, int rows2,
    const float* __restrict__ Wc, const float* __restrict__ bc, float* __restrict__ Cc,
    const float* __restrict__ Wd, const float* __restrict__ bd, float* __restrict__ Cd,
    int rowTiles1)
{
    constexpr int RPT = BM / 16;   // rows per thread (8 or 4)
    constexpr int NQA = BM / 64;   // A float4-quads per thread (2 or 1)
    const int tid = threadIdx.x;
    const int bx = blockIdx.x, by = blockIdx.y;

    const float* A; const float* W; const float* bias; float* C; int rows; int rowTile;
    const bool second = (by >= 2);           // cols 256..511 of the concat
    if (bx < rowTiles1) {
        A = A1; rows = rows1; rowTile = bx;
        W = second ? Wb : Wa; bias = second ? bb_ : ba; C = second ? Cb : Ca;
    } else {
        A = A2; rows = rows2; rowTile = bx - rowTiles1;
        W = second ? Wd : Wc; bias = second ? bd : bc; C = second ? Cd : Cc;
    }
    const int col0 = (by & 1) * 128;
    const int row0 = rowTile * BM;

    __shared__ float sA[16][BM + 4];
    __shared__ float sB[16][132];

    const int tx = tid & 15, ty = tid >> 4;

    float acc[RPT][8];
    #pragma unroll
    for (int i = 0; i < RPT; ++i)
        #pragma unroll
        for (int j = 0; j < 8; ++j) acc[i][j] = 0.f;

    float4 pa[NQA], pb[2];

    #define GLOAD(KT) do {                                                    \
        const int kk_ = (KT) * 16;                                            \
        _Pragma("unroll")                                                     \
        for (int q = 0; q < NQA; ++q) {                                       \
            int qq = tid + q * 256;                                           \
            int r = row0 + (qq >> 2); r = r < rows ? r : rows - 1;            \
            pa[q] = *(const float4*)&A[(size_t)r * 256 + kk_ + (qq & 3) * 4]; \
        }                                                                     \
        _Pragma("unroll")                                                     \
        for (int q = 0; q < 2; ++q) {                                         \
            int qq = tid + q * 256;                                           \
            int kr = qq >> 5, cq = qq & 31;                                   \
            pb[q] = *(const float4*)&W[(size_t)(kk_ + kr) * 256 + col0 + cq * 4]; \
        }                                                                     \
    } while (0)

    GLOAD(0);
    for (int kt = 0; kt < 16; ++kt) {
        __syncthreads();
        #pragma unroll
        for (int q = 0; q < NQA; ++q) {
            int qq = tid + q * 256;
            int ar = qq >> 2, ak = (qq & 3) * 4;
            sA[ak + 0][ar] = pa[q].x;
            sA[ak + 1][ar] = pa[q].y;
            sA[ak + 2][ar] = pa[q].z;
            sA[ak + 3][ar] = pa[q].w;
        }
        #pragma unroll
        for (int q = 0; q < 2; ++q) {
            int qq = tid + q * 256;
            int kr = qq >> 5, cq = qq & 31;
            *(float4*)&sB[kr][cq * 4] = pb[q];
        }
        __syncthreads();
        if (kt < 15) GLOAD(kt + 1);
        #pragma unroll
        for (int k = 0; k < 16; ++k) {
            float4 b0 = *(const float4*)&sB[k][tx * 4];
            float4 b1 = *(const float4*)&sB[k][tx * 4 + 64];
            float bv[8] = {b0.x, b0.y, b0.z, b0.w, b1.x, b1.y, b1.z, b1.w};
            float av[RPT];
            float4 a0 = *(const float4*)&sA[k][ty * 4];
            av[0] = a0.x; av[1] = a0.y; av[2] = a0.z; av[3] = a0.w;
            if (BM == 128) {
                float4 a1 = *(const float4*)&sA[k][ty * 4 + 64];
                av[4] = a1.x; av[5] = a1.y; av[6] = a1.z; av[7] = a1.w;
            }
            #pragma unroll
            for (int i = 0; i < RPT; ++i)
                #pragma unroll
                for (int j = 0; j < 8; ++j)
                    acc[i][j] = fmaf(av[i], bv[j], acc[i][j]);
        }
    }
    #undef GLOAD

    float4 bi0 = *(const float4*)&bias[col0 + tx * 4];
    float4 bi1 = *(const float4*)&bias[col0 + tx * 4 + 64];
    #pragma unroll
    for (int i = 0; i < RPT; ++i) {
        const int r = row0 + ty * 4 + ((i < 4) ? i : (64 + i - 4));
        if (r < rows) {
            float4 o0 = make_float4(acc[i][0] + bi0.x, acc[i][1] + bi0.y,
                                    acc[i][2] + bi0.z, acc[i][3] + bi0.w);
            float4 o1 = make_float4(acc[i][4] + bi1.x, acc[i][5] + bi1.y,
                                    acc[i][6] + bi1.z, acc[i][7] + bi1.w);
            *(float4*)&C[(size_t)r * 256 + col0 + tx * 4] = o0;
            *(float4*)&C[(size_t)r * 256 + col0 + tx * 4 + 64] = o1;
        }
    }
}

// ---------------------------------------------------------------------------
// Fused bilinear sampling + key-aware attention.
// Block = one (n,q). Phase 1: 128 threads compute per-(m,l,p) bilinear weights
// + element offsets once (was replicated 32x). Phase 2: 8 m-groups of 32
// lanes = 4 points x 8 d-quads; float4 gathers; octet shuffle reductions.
// ---------------------------------------------------------------------------
__global__ __launch_bounds__(256) void sample_attn(
    const float* __restrict__ qproj,   // [NB*LQN][256]  (m*32+d)
    const float* __restrict__ offp,    // [NB*LQN][256]  (m*32+l*8+p*2+c)
    const float* __restrict__ refp,    // [NB*LQN][4][2]
    const float* __restrict__ value,   // [NB][LIN][256]
    const float* __restrict__ keyf,    // [NB][LIN][256]
    float* __restrict__ outmid)        // [NB*LQN][256]
{
    const int bx = blockIdx.x;
    const int n = bx / LQN;
    const int tid = threadIdx.x;

    __shared__ float s_off[256];
    __shared__ float s_ref[8];
    __shared__ __align__(16) float s_w[8][16][4];
    __shared__ __align__(16) int   s_idx[8][16][4];

    const int baseq = bx * CC;
    s_off[tid] = offp[baseq + tid];
    if (tid < 8) s_ref[tid] = refp[bx * 8 + tid];
    __syncthreads();

    if (tid < 128) {
        const int pm = tid >> 4, l = (tid >> 2) & 3, p = tid & 3;
        const int HW = 64 >> l;
        const int st = (l == 0) ? 0 : (l == 1) ? 4096 : (l == 2) ? 5120 : 5376;
        const float fHW = (float)HW;
        float x = s_ref[l * 2 + 0] * fHW + s_off[pm * 32 + l * 8 + p * 2 + 0] - 0.5f;
        float y = s_ref[l * 2 + 1] * fHW + s_off[pm * 32 + l * 8 + p * 2 + 1] - 0.5f;
        float x0f = floorf(x), y0f = floorf(y);
        float txf = x - x0f, tyf = y - y0f;
        int x0 = (int)x0f, y0 = (int)y0f;
        int x1 = x0 + 1, y1 = y0 + 1;
        float fx0 = (x0 >= 0 && x0 < HW) ? (1.f - txf) : 0.f;
        float fx1 = (x1 >= 0 && x1 < HW) ? txf : 0.f;
        float fy0 = (y0 >= 0 && y0 < HW) ? (1.f - tyf) : 0.f;
        float fy1 = (y1 >= 0 && y1 < HW) ? tyf : 0.f;
        int xc0 = min(max(x0, 0), HW - 1), xc1 = min(max(x1, 0), HW - 1);
        int yc0 = min(max(y0, 0), HW - 1), yc1 = min(max(y1, 0), HW - 1);
        const int pt = l * 4 + p;
        s_w[pm][pt][0] = fx0 * fy0;
        s_w[pm][pt][1] = fx1 * fy0;
        s_w[pm][pt][2] = fx0 * fy1;
        s_w[pm][pt][3] = fx1 * fy1;
        const int eb = pm * 32;
        s_idx[pm][pt][0] = (st + yc0 * HW + xc0) * CC + eb;
        s_idx[pm][pt][1] = (st + yc0 * HW + xc1) * CC + eb;
        s_idx[pm][pt][2] = (st + yc1 * HW + xc0) * CC + eb;
        s_idx[pm][pt][3] = (st + yc1 * HW + xc1) * CC + eb;
    }
    __syncthreads();

    const int m = tid >> 5, lane = tid & 31;
    const int p2 = lane >> 3, dq = lane & 7;
    const size_t nbase = (size_t)n * LIN * CC;
    const float* vbp = value + nbase;
    const float* kbp = keyf + nbase;
    const int doff = dq * 4;

    const float4 q4 = *(const float4*)&qproj[baseq + m * 32 + doff];

    float lg[4];
    float4 vv[4];

    #pragma unroll
    for (int r = 0; r < 4; ++r) {
        const int pt = r * 4 + p2;
        float4 w4 = *(const float4*)&s_w[m][pt][0];
        int4  i4 = *(const int4*)&s_idx[m][pt][0];
        const float* ka = kbp + i4.x + doff;
        const float* kb = kbp + i4.y + doff;
        const float* kc = kbp + i4.z + doff;
        const float* kd = kbp + i4.w + doff;
        const float* va = vbp + i4.x + doff;
        const float* vb = vbp + i4.y + doff;
        const float* vc = vbp + i4.z + doff;
        const float* vd = vbp + i4.w + doff;
        float4 kA = *(const float4*)ka, kB = *(const float4*)kb;
        float4 kC = *(const float4*)kc, kD = *(const float4*)kd;
        float4 vA = *(const float4*)va, vB = *(const float4*)vb;
        float4 vC = *(const float4*)vc, vD = *(const float4*)vd;
        float4 ks;
        ks.x = fmaf(w4.w, kD.x, fmaf(w4.z, kC.x, fmaf(w4.y, kB.x, w4.x * kA.x)));
        ks.y = fmaf(w4.w, kD.y, fmaf(w4.z, kC.y, fmaf(w4.y, kB.y, w4.x * kA.y)));
        ks.z = fmaf(w4.w, kD.z, fmaf(w4.z, kC.z, fmaf(w4.y, kB.z, w4.x * kA.z)));
        ks.w = fmaf(w4.w, kD.w, fmaf(w4.z, kC.w, fmaf(w4.y, kB.w, w4.x * kA.w)));
        vv[r].x = fmaf(w4.w, vD.x, fmaf(w4.z, vC.x, fmaf(w4.y, vB.x, w4.x * vA.x)));
        vv[r].y = fmaf(w4.w, vD.y, fmaf(w4.z, vC.y, fmaf(w4.y, vB.y, w4.x * vA.y)));
        vv[r].z = fmaf(w4.w, vD.z, fmaf(w4.z, vC.z, fmaf(w4.y, vB.z, w4.x * vA.z)));
        vv[r].w = fmaf(w4.w, vD.w, fmaf(w4.z, vC.w, fmaf(w4.y, vB.w, w4.x * vA.w)));
        float s = fmaf(q4.w, ks.w, fmaf(q4.z, ks.z, fmaf(q4.y, ks.y, q4.x * ks.x)));
        s += __shfl_xor(s, 1);
        s += __shfl_xor(s, 2);
        s += __shfl_xor(s, 4);
        lg[r] = s * 0.17677669529663687f;   // 1/sqrt(32)
    }

    // softmax over 16 points (4 local x 4 p2-octets within the 32-lane group)
    float mx = fmaxf(fmaxf(lg[0], lg[1]), fmaxf(lg[2], lg[3]));
    mx = fmaxf(mx, __shfl_xor(mx, 8));
    mx = fmaxf(mx, __shfl_xor(mx, 16));
    float e0 = __expf(lg[0] - mx), e1 = __expf(lg[1] - mx);
    float e2 = __expf(lg[2] - mx), e3 = __expf(lg[3] - mx);
    float Z = e0 + e1 + e2 + e3;
    Z += __shfl_xor(Z, 8);
    Z += __shfl_xor(Z, 16);

    float4 o;
    o.x = fmaf(e3, vv[3].x, fmaf(e2, vv[2].x, fmaf(e1, vv[1].x, e0 * vv[0].x)));
    o.y = fmaf(e3, vv[3].y, fmaf(e2, vv[2].y, fmaf(e1, vv[1].y, e0 * vv[0].y)));
    o.z = fmaf(e3, vv[3].z, fmaf(e2, vv[2].z, fmaf(e1, vv[1].z, e0 * vv[0].z)));
    o.w = fmaf(e3, vv[3].w, fmaf(e2, vv[2].w, fmaf(e1, vv[1].w, e0 * vv[0].w)));
    #pragma unroll
    for (int msk = 8; msk <= 16; msk <<= 1) {
        o.x += __shfl_xor(o.x, msk);
        o.y += __shfl_xor(o.y, msk);
        o.z += __shfl_xor(o.z, msk);
        o.w += __shfl_xor(o.w, msk);
    }
    if (p2 == 0) {
        const float rz = 1.0f / Z;
        float4 res = make_float4(o.x * rz, o.y * rz, o.z * rz, o.w * rz);
        *(float4*)&outmid[baseq + m * 32 + doff] = res;
    }
}

extern "C" void kernel_launch(void* const* d_in, const int* in_sizes, int n_in,
                              void* d_out, int out_size, void* d_ws, size_t ws_size,
                              hipStream_t stream) {
    const float* query = (const float*)d_in[0];
    const float* refp  = (const float*)d_in[1];
    const float* xflat = (const float*)d_in[2];
    // d_in[3] spatial shapes, d_in[4] level starts: compile-time constants
    const float* Wv   = (const float*)d_in[5];
    const float* bv   = (const float*)d_in[6];
    const float* Wk   = (const float*)d_in[7];
    const float* bk   = (const float*)d_in[8];
    const float* Wq   = (const float*)d_in[9];
    const float* bq   = (const float*)d_in[10];
    const float* Woff = (const float*)d_in[11];
    const float* boff = (const float*)d_in[12];
    const float* Wout = (const float*)d_in[13];
    const float* bout = (const float*)d_in[14];

    char* ws = (char*)d_ws;
    float* value  = (float*)ws; ws += (size_t)NB * LIN * CC * sizeof(float);
    float* keyf   = (float*)ws; ws += (size_t)NB * LIN * CC * sizeof(float);
    float* qproj  = (float*)ws; ws += (size_t)NB * LQN * CC * sizeof(float);
    float* offp   = (float*)ws; ws += (size_t)NB * LQN * CC * sizeof(float);
    float* outmid = (float*)ws; ws += (size_t)NB * LQN * CC * sizeof(float);

    dim3 blk(256);

    // Fused projections: {xflat -> value|keyf} and {query -> qproj|offp}.
    // rowTiles: 10880/128 = 85, ceil(8000/128) = 63. Grid (148, 4).
    gemm_f32<128><<<dim3(85 + 63, 4), blk, 0, stream>>>(
        xflat, NB * LIN, Wv, bv, value, Wk, bk, keyf,
        query, NB * LQN, Wq, bq, qproj, Woff, boff, offp, 85);

    // fused deformable sampling + key-aware attention
    sample_attn<<<dim3(NB * LQN), blk, 0, stream>>>(qproj, offp, refp, value, keyf, outmid);

    // out = outmid @ Wout + bout -> f32 d_out.  BM=64: 125 row tiles x 2 col tiles.
    gemm_f32<64><<<dim3(125, 2), blk, 0, stream>>>(
        outmid, NB * LQN, Wout, bout, (float*)d_out,
        nullptr, nullptr, nullptr,
        nullptr, 0, nullptr, nullptr, nullptr, nullptr, nullptr, nullptr, 125);
}

// Round 6
// 241.105 us; speedup vs baseline: 1.0877x; 1.0003x over previous
//
#include <hip/hip_runtime.h>

// Problem constants (from reference setup_inputs)
#define NB   2
#define LQN  4000
#define CC   256     // C
#define LIN  5440    // sum of H*W over levels

typedef float f32x4 __attribute__((ext_vector_type(4)));

// ---------------------------------------------------------------------------
// GEMM: C = A @ W + b, K=N=256, up to two A-problems, each with a 512-col
// concatenated weight pair [Wa|Wb] / [Wc|Wd].
// BM=64, BN=128, BK=32, 256 threads, per-thread 4 rows x 8 cols (split col
// quads tx*4 / tx*4+64). All row counts divide 64 exactly -> no edge guards.
// Register prefetch of next K-tile overlaps LDS compute.
// ---------------------------------------------------------------------------
__global__ __launch_bounds__(256) void gemm_f32(
    const float* __restrict__ A1, int rowTiles1,
    const float* __restrict__ Wa, const float* __restrict__ ba, float* __restrict__ Ca,
    const float* __restrict__ Wb, const float* __restrict__ bb_, float* __restrict__ Cb,
    const float* __restrict__ A2,
    const float* __restrict__ Wc, const float* __restrict__ bc, float* __restrict__ Cc,
    const float* __restrict__ Wd, const float* __restrict__ bd, float* __restrict__ Cd)
{
    const int tid = threadIdx.x;
    const int bx = blockIdx.x, by = blockIdx.y;

    const float* A; const float* W; const float* bias; float* C; int rowTile;
    const bool second = (by >= 2);           // cols 256..511 of the concat
    if (bx < rowTiles1) {
        A = A1; rowTile = bx;
        W = second ? Wb : Wa; bias = second ? bb_ : ba; C = second ? Cb : Ca;
    } else {
        A = A2; rowTile = bx - rowTiles1;
        W = second ? Wd : Wc; bias = second ? bd : bc; C = second ? Cd : Cc;
    }
    const int col0 = (by & 1) * 128;
    const int row0 = rowTile * 64;

    __shared__ float sA[32][68];    // [k][m]
    __shared__ float sB[32][132];   // [k][n]

    const int tx = tid & 15, ty = tid >> 4;

    float acc[4][8];
    #pragma unroll
    for (int i = 0; i < 4; ++i)
        #pragma unroll
        for (int j = 0; j < 8; ++j) acc[i][j] = 0.f;

    // A: 64 rows x 32 k = 512 float4 -> 2/thread.  qq=tid+q*256: r=qq>>3, kq=(qq&7)*4
    // B: 32 k x 128 cols = 1024 float4 -> 4/thread. qq: kr=qq>>5, cq=qq&31
    float4 pa[2], pb[4];

    #define GLOAD(KT) do {                                                        \
        const int kk_ = (KT) * 32;                                                \
        _Pragma("unroll")                                                         \
        for (int q = 0; q < 2; ++q) {                                             \
            int qq = tid + q * 256;                                               \
            pa[q] = *(const float4*)&A[(size_t)(row0 + (qq >> 3)) * 256 + kk_ + (qq & 7) * 4]; \
        }                                                                         \
        _Pragma("unroll")                                                         \
        for (int q = 0; q < 4; ++q) {                                             \
            int qq = tid + q * 256;                                               \
            pb[q] = *(const float4*)&W[(size_t)(kk_ + (qq >> 5)) * 256 + col0 + (qq & 31) * 4]; \
        }                                                                         \
    } while (0)

    GLOAD(0);
    for (int kt = 0; kt < 8; ++kt) {
        __syncthreads();
        #pragma unroll
        for (int q = 0; q < 2; ++q) {
            int qq = tid + q * 256;
            int ar = qq >> 3, ak = (qq & 7) * 4;
            sA[ak + 0][ar] = pa[q].x;
            sA[ak + 1][ar] = pa[q].y;
            sA[ak + 2][ar] = pa[q].z;
            sA[ak + 3][ar] = pa[q].w;
        }
        #pragma unroll
        for (int q = 0; q < 4; ++q) {
            int qq = tid + q * 256;
            *(float4*)&sB[qq >> 5][(qq & 31) * 4] = pb[q];
        }
        __syncthreads();
        if (kt < 7) GLOAD(kt + 1);
        #pragma unroll
        for (int k = 0; k < 32; ++k) {
            float4 a0 = *(const float4*)&sA[k][ty * 4];
            float4 b0 = *(const float4*)&sB[k][tx * 4];
            float4 b1 = *(const float4*)&sB[k][tx * 4 + 64];
            float av[4] = {a0.x, a0.y, a0.z, a0.w};
            float bv[8] = {b0.x, b0.y, b0.z, b0.w, b1.x, b1.y, b1.z, b1.w};
            #pragma unroll
            for (int i = 0; i < 4; ++i)
                #pragma unroll
                for (int j = 0; j < 8; ++j)
                    acc[i][j] = fmaf(av[i], bv[j], acc[i][j]);
        }
    }
    #undef GLOAD

    float4 bi0 = *(const float4*)&bias[col0 + tx * 4];
    float4 bi1 = *(const float4*)&bias[col0 + tx * 4 + 64];
    #pragma unroll
    for (int i = 0; i < 4; ++i) {
        const int r = row0 + ty * 4 + i;
        float4 o0 = make_float4(acc[i][0] + bi0.x, acc[i][1] + bi0.y,
                                acc[i][2] + bi0.z, acc[i][3] + bi0.w);
        float4 o1 = make_float4(acc[i][4] + bi1.x, acc[i][5] + bi1.y,
                                acc[i][6] + bi1.z, acc[i][7] + bi1.w);
        *(float4*)&C[(size_t)r * 256 + col0 + tx * 4] = o0;
        *(float4*)&C[(size_t)r * 256 + col0 + tx * 4 + 64] = o1;
    }
}

// ---------------------------------------------------------------------------
// Fused bilinear sampling + key-aware attention (unchanged from round 5).
// ---------------------------------------------------------------------------
__global__ __launch_bounds__(256) void sample_attn(
    const float* __restrict__ qproj,   // [NB*LQN][256]  (m*32+d)
    const float* __restrict__ offp,    // [NB*LQN][256]  (m*32+l*8+p*2+c)
    const float* __restrict__ refp,    // [NB*LQN][4][2]
    const float* __restrict__ value,   // [NB][LIN][256]
    const float* __restrict__ keyf,    // [NB][LIN][256]
    float* __restrict__ outmid)        // [NB*LQN][256]
{
    const int bx = blockIdx.x;
    const int n = bx / LQN;
    const int tid = threadIdx.x;

    __shared__ float s_off[256];
    __shared__ float s_ref[8];
    __shared__ __align__(16) float s_w[8][16][4];
    __shared__ __align__(16) int   s_idx[8][16][4];

    const int baseq = bx * CC;
    s_off[tid] = offp[baseq + tid];
    if (tid < 8) s_ref[tid] = refp[bx * 8 + tid];
    __syncthreads();

    if (tid < 128) {
        const int pm = tid >> 4, l = (tid >> 2) & 3, p = tid & 3;
        const int HW = 64 >> l;
        const int st = (l == 0) ? 0 : (l == 1) ? 4096 : (l == 2) ? 5120 : 5376;
        const float fHW = (float)HW;
        float x = s_ref[l * 2 + 0] * fHW + s_off[pm * 32 + l * 8 + p * 2 + 0] - 0.5f;
        float y = s_ref[l * 2 + 1] * fHW + s_off[pm * 32 + l * 8 + p * 2 + 1] - 0.5f;
        float x0f = floorf(x), y0f = floorf(y);
        float txf = x - x0f, tyf = y - y0f;
        int x0 = (int)x0f, y0 = (int)y0f;
        int x1 = x0 + 1, y1 = y0 + 1;
        float fx0 = (x0 >= 0 && x0 < HW) ? (1.f - txf) : 0.f;
        float fx1 = (x1 >= 0 && x1 < HW) ? txf : 0.f;
        float fy0 = (y0 >= 0 && y0 < HW) ? (1.f - tyf) : 0.f;
        float fy1 = (y1 >= 0 && y1 < HW) ? tyf : 0.f;
        int xc0 = min(max(x0, 0), HW - 1), xc1 = min(max(x1, 0), HW - 1);
        int yc0 = min(max(y0, 0), HW - 1), yc1 = min(max(y1, 0), HW - 1);
        const int pt = l * 4 + p;
        s_w[pm][pt][0] = fx0 * fy0;
        s_w[pm][pt][1] = fx1 * fy0;
        s_w[pm][pt][2] = fx0 * fy1;
        s_w[pm][pt][3] = fx1 * fy1;
        const int eb = pm * 32;
        s_idx[pm][pt][0] = (st + yc0 * HW + xc0) * CC + eb;
        s_idx[pm][pt][1] = (st + yc0 * HW + xc1) * CC + eb;
        s_idx[pm][pt][2] = (st + yc1 * HW + xc0) * CC + eb;
        s_idx[pm][pt][3] = (st + yc1 * HW + xc1) * CC + eb;
    }
    __syncthreads();

    const int m = tid >> 5, lane = tid & 31;
    const int p2 = lane >> 3, dq = lane & 7;
    const size_t nbase = (size_t)n * LIN * CC;
    const float* vbp = value + nbase;
    const float* kbp = keyf + nbase;
    const int doff = dq * 4;

    const float4 q4 = *(const float4*)&qproj[baseq + m * 32 + doff];

    float lg[4];
    float4 vv[4];

    #pragma unroll
    for (int r = 0; r < 4; ++r) {
        const int pt = r * 4 + p2;
        float4 w4 = *(const float4*)&s_w[m][pt][0];
        int4  i4 = *(const int4*)&s_idx[m][pt][0];
        float4 kA = *(const float4*)(kbp + i4.x + doff);
        float4 kB = *(const float4*)(kbp + i4.y + doff);
        float4 kC = *(const float4*)(kbp + i4.z + doff);
        float4 kD = *(const float4*)(kbp + i4.w + doff);
        float4 vA = *(const float4*)(vbp + i4.x + doff);
        float4 vB = *(const float4*)(vbp + i4.y + doff);
        float4 vC = *(const float4*)(vbp + i4.z + doff);
        float4 vD = *(const float4*)(vbp + i4.w + doff);
        float4 ks;
        ks.x = fmaf(w4.w, kD.x, fmaf(w4.z, kC.x, fmaf(w4.y, kB.x, w4.x * kA.x)));
        ks.y = fmaf(w4.w, kD.y, fmaf(w4.z, kC.y, fmaf(w4.y, kB.y, w4.x * kA.y)));
        ks.z = fmaf(w4.w, kD.z, fmaf(w4.z, kC.z, fmaf(w4.y, kB.z, w4.x * kA.z)));
        ks.w = fmaf(w4.w, kD.w, fmaf(w4.z, kC.w, fmaf(w4.y, kB.w, w4.x * kA.w)));
        vv[r].x = fmaf(w4.w, vD.x, fmaf(w4.z, vC.x, fmaf(w4.y, vB.x, w4.x * vA.x)));
        vv[r].y = fmaf(w4.w, vD.y, fmaf(w4.z, vC.y, fmaf(w4.y, vB.y, w4.x * vA.y)));
        vv[r].z = fmaf(w4.w, vD.z, fmaf(w4.z, vC.z, fmaf(w4.y, vB.z, w4.x * vA.z)));
        vv[r].w = fmaf(w4.w, vD.w, fmaf(w4.z, vC.w, fmaf(w4.y, vB.w, w4.x * vA.w)));
        float s = fmaf(q4.w, ks.w, fmaf(q4.z, ks.z, fmaf(q4.y, ks.y, q4.x * ks.x)));
        s += __shfl_xor(s, 1);
        s += __shfl_xor(s, 2);
        s += __shfl_xor(s, 4);
        lg[r] = s * 0.17677669529663687f;   // 1/sqrt(32)
    }

    float mx = fmaxf(fmaxf(lg[0], lg[1]), fmaxf(lg[2], lg[3]));
    mx = fmaxf(mx, __shfl_xor(mx, 8));
    mx = fmaxf(mx, __shfl_xor(mx, 16));
    float e0 = __expf(lg[0] - mx), e1 = __expf(lg[1] - mx);
    float e2 = __expf(lg[2] - mx), e3 = __expf(lg[3] - mx);
    float Z = e0 + e1 + e2 + e3;
    Z += __shfl_xor(Z, 8);
    Z += __shfl_xor(Z, 16);

    float4 o;
    o.x = fmaf(e3, vv[3].x, fmaf(e2, vv[2].x, fmaf(e1, vv[1].x, e0 * vv[0].x)));
    o.y = fmaf(e3, vv[3].y, fmaf(e2, vv[2].y, fmaf(e1, vv[1].y, e0 * vv[0].y)));
    o.z = fmaf(e3, vv[3].z, fmaf(e2, vv[2].z, fmaf(e1, vv[1].z, e0 * vv[0].z)));
    o.w = fmaf(e3, vv[3].w, fmaf(e2, vv[2].w, fmaf(e1, vv[1].w, e0 * vv[0].w)));
    #pragma unroll
    for (int msk = 8; msk <= 16; msk <<= 1) {
        o.x += __shfl_xor(o.x, msk);
        o.y += __shfl_xor(o.y, msk);
        o.z += __shfl_xor(o.z, msk);
        o.w += __shfl_xor(o.w, msk);
    }
    if (p2 == 0) {
        const float rz = 1.0f / Z;
        float4 res = make_float4(o.x * rz, o.y * rz, o.z * rz, o.w * rz);
        *(float4*)&outmid[baseq + m * 32 + doff] = res;
    }
}

extern "C" void kernel_launch(void* const* d_in, const int* in_sizes, int n_in,
                              void* d_out, int out_size, void* d_ws, size_t ws_size,
                              hipStream_t stream) {
    const float* query = (const float*)d_in[0];
    const float* refp  = (const float*)d_in[1];
    const float* xflat = (const float*)d_in[2];
    // d_in[3] spatial shapes, d_in[4] level starts: compile-time constants
    const float* Wv   = (const float*)d_in[5];
    const float* bv   = (const float*)d_in[6];
    const float* Wk   = (const float*)d_in[7];
    const float* bk   = (const float*)d_in[8];
    const float* Wq   = (const float*)d_in[9];
    const float* bq   = (const float*)d_in[10];
    const float* Woff = (const float*)d_in[11];
    const float* boff = (const float*)d_in[12];
    const float* Wout = (const float*)d_in[13];
    const float* bout = (const float*)d_in[14];

    char* ws = (char*)d_ws;
    float* value  = (float*)ws; ws += (size_t)NB * LIN * CC * sizeof(float);
    float* keyf   = (float*)ws; ws += (size_t)NB * LIN * CC * sizeof(float);
    float* qproj  = (float*)ws; ws += (size_t)NB * LQN * CC * sizeof(float);
    float* offp   = (float*)ws; ws += (size_t)NB * LQN * CC * sizeof(float);
    float* outmid = (float*)ws; ws += (size_t)NB * LQN * CC * sizeof(float);

    dim3 blk(256);

    // Fused projections: {xflat -> value|keyf} and {query -> qproj|offp}.
    // Row tiles: 10880/64 = 170, 8000/64 = 125. Grid (295, 4) = 1180 blocks.
    gemm_f32<<<dim3(170 + 125, 4), blk, 0, stream>>>(
        xflat, 170, Wv, bv, value, Wk, bk, keyf,
        query, Wq, bq, qproj, Woff, boff, offp);

    // fused deformable sampling + key-aware attention
    sample_attn<<<dim3(NB * LQN), blk, 0, stream>>>(qproj, offp, refp, value, keyf, outmid);

    // out = outmid @ Wout + bout -> f32 d_out. Grid (125, 2) = 250 blocks.
    gemm_f32<<<dim3(125, 2), blk, 0, stream>>>(
        outmid, 125, Wout, bout, (float*)d_out,
        nullptr, nullptr, nullptr,
        nullptr, nullptr, nullptr, nullptr, nullptr, nullptr, nullptr);
}

// Round 7
// 216.381 us; speedup vs baseline: 1.2119x; 1.1143x over previous
//
#include <hip/hip_runtime.h>

// Problem constants (from reference setup_inputs)
#define NB   2
#define LQN  4000
#define CC   256     // C
#define LIN  5440    // sum of H*W over levels

typedef short bf16x8 __attribute__((ext_vector_type(8)));   // 8 bf16 = 4 VGPR
typedef float f32x4 __attribute__((ext_vector_type(4)));    // MFMA C/D

__device__ __forceinline__ unsigned short f2b(float f) {    // f32 -> bf16 RNE
    union { float f; unsigned u; } v; v.f = f;
    unsigned r = v.u + 0x7FFFu + ((v.u >> 16) & 1u);
    return (unsigned short)(r >> 16);
}

// ---------------------------------------------------------------------------
// One-time: transpose the 4 projection weights (f32 [k][n]) to bf16 [n][k].
// grid (256, 4): by = matrix, bx = output row n, tid = k.
// ---------------------------------------------------------------------------
__global__ void weights_T(const float* __restrict__ Wv, const float* __restrict__ Wk,
                          const float* __restrict__ Wq, const float* __restrict__ Wo,
                          unsigned short* __restrict__ WT)
{
    const int my = blockIdx.y;
    const float* W = (my == 0) ? Wv : (my == 1) ? Wk : (my == 2) ? Wq : Wo;
    const int n = blockIdx.x, k = threadIdx.x;
    WT[my * 65536 + n * 256 + k] = f2b(W[k * 256 + n]);
}

// ---------------------------------------------------------------------------
// Projection GEMM, bf16 MFMA: C = A @ W + b, K=256, N=256, f32 in/out.
// BM=64, BN=256 (full W), BK=32. 256 threads = 4 waves; wave (wid&1) owns
// rows 32*(wid&1)..+32, (wid>>1) owns cols 128*(wid>>1)..+128 -> 2x8 tiles of
// 16x16x32 MFMA per K-step. A staged f32->bf16; W pre-transposed bf16 [n][k].
// ---------------------------------------------------------------------------
__global__ __launch_bounds__(256) void gemm_mfma(
    const float* __restrict__ A1, const float* __restrict__ A2,
    const unsigned short* __restrict__ WT,
    const float* __restrict__ bv, const float* __restrict__ bk,
    const float* __restrict__ bq, const float* __restrict__ bo,
    float* __restrict__ value, float* __restrict__ keyf,
    float* __restrict__ qproj, float* __restrict__ offp)
{
    const int bx = blockIdx.x, by = blockIdx.y;
    const float* A; float* C; const float* bias; int mat, row0;
    if (bx < 170) { A = A1; row0 = bx * 64;        mat = by;     C = by ? keyf : value; bias = by ? bk : bv; }
    else          { A = A2; row0 = (bx - 170) * 64; mat = 2 + by; C = by ? offp : qproj; bias = by ? bo : bq; }
    const unsigned short* __restrict__ WTm = WT + mat * 65536;

    __shared__ __align__(16) unsigned short sA[64 * 40];    // [m][k] bf16, stride 40
    __shared__ __align__(16) unsigned short sB[256 * 40];   // [n][k] bf16, stride 40

    const int tid = threadIdx.x;
    const int wid = tid >> 6, lane = tid & 63;
    const int m16 = lane & 15, q = lane >> 4;
    const int wr0 = (wid & 1) * 32, wc0 = (wid >> 1) * 128;

    f32x4 acc[2][8];
    #pragma unroll
    for (int i = 0; i < 2; ++i)
        #pragma unroll
        for (int j = 0; j < 8; ++j) acc[i][j] = (f32x4){0.f, 0.f, 0.f, 0.f};

    const int ar = tid >> 2, akq = tid & 3;   // A staging: row, k-octet

    float4 pa0, pa1; int4 pbv[4];

    #define GLOAD(KT) do {                                                         \
        const int kk_ = (KT) * 32;                                                 \
        const float* ap_ = &A[(size_t)(row0 + ar) * 256 + kk_ + akq * 8];          \
        pa0 = *(const float4*)ap_;                                                 \
        pa1 = *(const float4*)(ap_ + 4);                                           \
        _Pragma("unroll")                                                          \
        for (int qI = 0; qI < 4; ++qI) {                                           \
            int c = tid + qI * 256;                                                \
            pbv[qI] = *(const int4*)&WTm[(c >> 2) * 256 + kk_ + (c & 3) * 8];      \
        }                                                                          \
    } while (0)

    GLOAD(0);
    for (int kt = 0; kt < 8; ++kt) {
        __syncthreads();
        {
            bf16x8 af;
            af[0] = (short)f2b(pa0.x); af[1] = (short)f2b(pa0.y);
            af[2] = (short)f2b(pa0.z); af[3] = (short)f2b(pa0.w);
            af[4] = (short)f2b(pa1.x); af[5] = (short)f2b(pa1.y);
            af[6] = (short)f2b(pa1.z); af[7] = (short)f2b(pa1.w);
            *(bf16x8*)&sA[ar * 40 + akq * 8] = af;
            #pragma unroll
            for (int qI = 0; qI < 4; ++qI) {
                int c = tid + qI * 256;
                *(int4*)&sB[(c >> 2) * 40 + (c & 3) * 8] = pbv[qI];
            }
        }
        __syncthreads();
        if (kt < 7) GLOAD(kt + 1);
        bf16x8 aF[2], bF[8];
        #pragma unroll
        for (int rt = 0; rt < 2; ++rt)
            aF[rt] = *(const bf16x8*)&sA[(wr0 + rt * 16 + m16) * 40 + q * 8];
        #pragma unroll
        for (int ct = 0; ct < 8; ++ct)
            bF[ct] = *(const bf16x8*)&sB[(wc0 + ct * 16 + m16) * 40 + q * 8];
        #pragma unroll
        for (int rt = 0; rt < 2; ++rt)
            #pragma unroll
            for (int ct = 0; ct < 8; ++ct)
                acc[rt][ct] = __builtin_amdgcn_mfma_f32_16x16x32_bf16(
                    aF[rt], bF[ct], acc[rt][ct], 0, 0, 0);
    }
    #undef GLOAD

    // C/D layout: col = lane&15, row = q*4 + e  (m89-verified)
    #pragma unroll
    for (int ct = 0; ct < 8; ++ct) {
        const int col = wc0 + ct * 16 + m16;
        const float bcol = bias[col];
        #pragma unroll
        for (int rt = 0; rt < 2; ++rt) {
            #pragma unroll
            for (int e = 0; e < 4; ++e) {
                const int r = row0 + wr0 + rt * 16 + q * 4 + e;
                C[(size_t)r * 256 + col] = acc[rt][ct][e] + bcol;
            }
        }
    }
}

// ---------------------------------------------------------------------------
// Output GEMM, f32: C = A @ W + b. BM=16, BN=128, BK=32, 256 threads.
// grid (500, 2) = 1000 blocks -> ~16 waves/CU (was 250 blocks, latency-bound).
// ---------------------------------------------------------------------------
__global__ __launch_bounds__(256) void gemm_out(
    const float* __restrict__ A, const float* __restrict__ W,
    const float* __restrict__ bias, float* __restrict__ C)
{
    const int row0 = blockIdx.x * 16;
    const int col0 = blockIdx.y * 128;
    __shared__ float sA[32][20];    // [k][m]
    __shared__ float sB[32][132];   // [k][n]
    const int tid = threadIdx.x;
    const int tx = tid & 31, ty = tid >> 5;

    float acc[2][4] = {};
    float4 pa; float4 pb[4];

    #define GLOAD(KT) do {                                                        \
        const int kk_ = (KT) * 32;                                                \
        if (tid < 128)                                                            \
            pa = *(const float4*)&A[(size_t)(row0 + (tid >> 3)) * 256 + kk_ + (tid & 7) * 4]; \
        _Pragma("unroll")                                                         \
        for (int qI = 0; qI < 4; ++qI) {                                          \
            int c = tid + qI * 256;                                               \
            pb[qI] = *(const float4*)&W[(size_t)(kk_ + (c >> 5)) * 256 + col0 + (c & 31) * 4]; \
        }                                                                         \
    } while (0)

    GLOAD(0);
    for (int kt = 0; kt < 8; ++kt) {
        __syncthreads();
        if (tid < 128) {
            const int r = tid >> 3, kq = (tid & 7) * 4;
            sA[kq + 0][r] = pa.x; sA[kq + 1][r] = pa.y;
            sA[kq + 2][r] = pa.z; sA[kq + 3][r] = pa.w;
        }
        #pragma unroll
        for (int qI = 0; qI < 4; ++qI) {
            int c = tid + qI * 256;
            *(float4*)&sB[c >> 5][(c & 31) * 4] = pb[qI];
        }
        __syncthreads();
        if (kt < 7) GLOAD(kt + 1);
        #pragma unroll
        for (int k = 0; k < 32; ++k) {
            float a0 = sA[k][ty], a1 = sA[k][ty + 8];
            float4 b = *(const float4*)&sB[k][tx * 4];
            acc[0][0] = fmaf(a0, b.x, acc[0][0]); acc[0][1] = fmaf(a0, b.y, acc[0][1]);
            acc[0][2] = fmaf(a0, b.z, acc[0][2]); acc[0][3] = fmaf(a0, b.w, acc[0][3]);
            acc[1][0] = fmaf(a1, b.x, acc[1][0]); acc[1][1] = fmaf(a1, b.y, acc[1][1]);
            acc[1][2] = fmaf(a1, b.z, acc[1][2]); acc[1][3] = fmaf(a1, b.w, acc[1][3]);
        }
    }
    #undef GLOAD

    float4 bi = *(const float4*)&bias[col0 + tx * 4];
    #pragma unroll
    for (int i = 0; i < 2; ++i) {
        const int r = row0 + ty + i * 8;
        float4 o = make_float4(acc[i][0] + bi.x, acc[i][1] + bi.y,
                               acc[i][2] + bi.z, acc[i][3] + bi.w);
        *(float4*)&C[(size_t)r * 256 + col0 + tx * 4] = o;
    }
}

// ---------------------------------------------------------------------------
// Fused bilinear sampling + key-aware attention (unchanged from round 6).
// ---------------------------------------------------------------------------
__global__ __launch_bounds__(256) void sample_attn(
    const float* __restrict__ qproj,   // [NB*LQN][256]  (m*32+d)
    const float* __restrict__ offp,    // [NB*LQN][256]  (m*32+l*8+p*2+c)
    const float* __restrict__ refp,    // [NB*LQN][4][2]
    const float* __restrict__ value,   // [NB][LIN][256]
    const float* __restrict__ keyf,    // [NB][LIN][256]
    float* __restrict__ outmid)        // [NB*LQN][256]
{
    const int bx = blockIdx.x;
    const int n = bx / LQN;
    const int tid = threadIdx.x;

    __shared__ float s_off[256];
    __shared__ float s_ref[8];
    __shared__ __align__(16) float s_w[8][16][4];
    __shared__ __align__(16) int   s_idx[8][16][4];

    const int baseq = bx * CC;
    s_off[tid] = offp[baseq + tid];
    if (tid < 8) s_ref[tid] = refp[bx * 8 + tid];
    __syncthreads();

    if (tid < 128) {
        const int pm = tid >> 4, l = (tid >> 2) & 3, p = tid & 3;
        const int HW = 64 >> l;
        const int st = (l == 0) ? 0 : (l == 1) ? 4096 : (l == 2) ? 5120 : 5376;
        const float fHW = (float)HW;
        float x = s_ref[l * 2 + 0] * fHW + s_off[pm * 32 + l * 8 + p * 2 + 0] - 0.5f;
        float y = s_ref[l * 2 + 1] * fHW + s_off[pm * 32 + l * 8 + p * 2 + 1] - 0.5f;
        float x0f = floorf(x), y0f = floorf(y);
        float txf = x - x0f, tyf = y - y0f;
        int x0 = (int)x0f, y0 = (int)y0f;
        int x1 = x0 + 1, y1 = y0 + 1;
        float fx0 = (x0 >= 0 && x0 < HW) ? (1.f - txf) : 0.f;
        float fx1 = (x1 >= 0 && x1 < HW) ? txf : 0.f;
        float fy0 = (y0 >= 0 && y0 < HW) ? (1.f - tyf) : 0.f;
        float fy1 = (y1 >= 0 && y1 < HW) ? tyf : 0.f;
        int xc0 = min(max(x0, 0), HW - 1), xc1 = min(max(x1, 0), HW - 1);
        int yc0 = min(max(y0, 0), HW - 1), yc1 = min(max(y1, 0), HW - 1);
        const int pt = l * 4 + p;
        s_w[pm][pt][0] = fx0 * fy0;
        s_w[pm][pt][1] = fx1 * fy0;
        s_w[pm][pt][2] = fx0 * fy1;
        s_w[pm][pt][3] = fx1 * fy1;
        const int eb = pm * 32;
        s_idx[pm][pt][0] = (st + yc0 * HW + xc0) * CC + eb;
        s_idx[pm][pt][1] = (st + yc0 * HW + xc1) * CC + eb;
        s_idx[pm][pt][2] = (st + yc1 * HW + xc0) * CC + eb;
        s_idx[pm][pt][3] = (st + yc1 * HW + xc1) * CC + eb;
    }
    __syncthreads();

    const int m = tid >> 5, lane = tid & 31;
    const int p2 = lane >> 3, dq = lane & 7;
    const size_t nbase = (size_t)n * LIN * CC;
    const float* vbp = value + nbase;
    const float* kbp = keyf + nbase;
    const int doff = dq * 4;

    const float4 q4 = *(const float4*)&qproj[baseq + m * 32 + doff];

    float lg[4];
    float4 vv[4];

    #pragma unroll
    for (int r = 0; r < 4; ++r) {
        const int pt = r * 4 + p2;
        float4 w4 = *(const float4*)&s_w[m][pt][0];
        int4  i4 = *(const int4*)&s_idx[m][pt][0];
        float4 kA = *(const float4*)(kbp + i4.x + doff);
        float4 kB = *(const float4*)(kbp + i4.y + doff);
        float4 kC = *(const float4*)(kbp + i4.z + doff);
        float4 kD = *(const float4*)(kbp + i4.w + doff);
        float4 vA = *(const float4*)(vbp + i4.x + doff);
        float4 vB = *(const float4*)(vbp + i4.y + doff);
        float4 vC = *(const float4*)(vbp + i4.z + doff);
        float4 vD = *(const float4*)(vbp + i4.w + doff);
        float4 ks;
        ks.x = fmaf(w4.w, kD.x, fmaf(w4.z, kC.x, fmaf(w4.y, kB.x, w4.x * kA.x)));
        ks.y = fmaf(w4.w, kD.y, fmaf(w4.z, kC.y, fmaf(w4.y, kB.y, w4.x * kA.y)));
        ks.z = fmaf(w4.w, kD.z, fmaf(w4.z, kC.z, fmaf(w4.y, kB.z, w4.x * kA.z)));
        ks.w = fmaf(w4.w, kD.w, fmaf(w4.z, kC.w, fmaf(w4.y, kB.w, w4.x * kA.w)));
        vv[r].x = fmaf(w4.w, vD.x, fmaf(w4.z, vC.x, fmaf(w4.y, vB.x, w4.x * vA.x)));
        vv[r].y = fmaf(w4.w, vD.y, fmaf(w4.z, vC.y, fmaf(w4.y, vB.y, w4.x * vA.y)));
        vv[r].z = fmaf(w4.w, vD.z, fmaf(w4.z, vC.z, fmaf(w4.y, vB.z, w4.x * vA.z)));
        vv[r].w = fmaf(w4.w, vD.w, fmaf(w4.z, vC.w, fmaf(w4.y, vB.w, w4.x * vA.w)));
        float s = fmaf(q4.w, ks.w, fmaf(q4.z, ks.z, fmaf(q4.y, ks.y, q4.x * ks.x)));
        s += __shfl_xor(s, 1);
        s += __shfl_xor(s, 2);
        s += __shfl_xor(s, 4);
        lg[r] = s * 0.17677669529663687f;   // 1/sqrt(32)
    }

    float mx = fmaxf(fmaxf(lg[0], lg[1]), fmaxf(lg[2], lg[3]));
    mx = fmaxf(mx, __shfl_xor(mx, 8));
    mx = fmaxf(mx, __shfl_xor(mx, 16));
    float e0 = __expf(lg[0] - mx), e1 = __expf(lg[1] - mx);
    float e2 = __expf(lg[2] - mx), e3 = __expf(lg[3] - mx);
    float Z = e0 + e1 + e2 + e3;
    Z += __shfl_xor(Z, 8);
    Z += __shfl_xor(Z, 16);

    float4 o;
    o.x = fmaf(e3, vv[3].x, fmaf(e2, vv[2].x, fmaf(e1, vv[1].x, e0 * vv[0].x)));
    o.y = fmaf(e3, vv[3].y, fmaf(e2, vv[2].y, fmaf(e1, vv[1].y, e0 * vv[0].y)));
    o.z = fmaf(e3, vv[3].z, fmaf(e2, vv[2].z, fmaf(e1, vv[1].z, e0 * vv[0].z)));
    o.w = fmaf(e3, vv[3].w, fmaf(e2, vv[2].w, fmaf(e1, vv[1].w, e0 * vv[0].w)));
    #pragma unroll
    for (int msk = 8; msk <= 16; msk <<= 1) {
        o.x += __shfl_xor(o.x, msk);
        o.y += __shfl_xor(o.y, msk);
        o.z += __shfl_xor(o.z, msk);
        o.w += __shfl_xor(o.w, msk);
    }
    if (p2 == 0) {
        const float rz = 1.0f / Z;
        float4 res = make_float4(o.x * rz, o.y * rz, o.z * rz, o.w * rz);
        *(float4*)&outmid[baseq + m * 32 + doff] = res;
    }
}

extern "C" void kernel_launch(void* const* d_in, const int* in_sizes, int n_in,
                              void* d_out, int out_size, void* d_ws, size_t ws_size,
                              hipStream_t stream) {
    const float* query = (const float*)d_in[0];
    const float* refp  = (const float*)d_in[1];
    const float* xflat = (const float*)d_in[2];
    // d_in[3] spatial shapes, d_in[4] level starts: compile-time constants
    const float* Wv   = (const float*)d_in[5];
    const float* bv   = (const float*)d_in[6];
    const float* Wk   = (const float*)d_in[7];
    const float* bk   = (const float*)d_in[8];
    const float* Wq   = (const float*)d_in[9];
    const float* bq   = (const float*)d_in[10];
    const float* Woff = (const float*)d_in[11];
    const float* boff = (const float*)d_in[12];
    const float* Wout = (const float*)d_in[13];
    const float* bout = (const float*)d_in[14];

    char* ws = (char*)d_ws;
    float* value  = (float*)ws; ws += (size_t)NB * LIN * CC * sizeof(float);
    float* keyf   = (float*)ws; ws += (size_t)NB * LIN * CC * sizeof(float);
    float* qproj  = (float*)ws; ws += (size_t)NB * LQN * CC * sizeof(float);
    float* offp   = (float*)ws; ws += (size_t)NB * LQN * CC * sizeof(float);
    float* outmid = (float*)ws; ws += (size_t)NB * LQN * CC * sizeof(float);
    // WT (4 x 256x256 bf16 = 512 KB) aliases outmid: consumed by gemm_mfma
    // strictly before sample_attn overwrites outmid.
    unsigned short* WT = (unsigned short*)outmid;

    dim3 blk(256);

    // 1) transpose projection weights to bf16 [n][k]
    weights_T<<<dim3(256, 4), blk, 0, stream>>>(Wv, Wk, Wq, Woff, WT);

    // 2) fused projections via MFMA: {xflat -> value|keyf}, {query -> qproj|offp}
    gemm_mfma<<<dim3(170 + 125, 2), blk, 0, stream>>>(
        xflat, query, WT, bv, bk, bq, boff, value, keyf, qproj, offp);

    // 3) fused deformable sampling + key-aware attention
    sample_attn<<<dim3(NB * LQN), blk, 0, stream>>>(qproj, offp, refp, value, keyf, outmid);

    // 4) out = outmid @ Wout + bout -> f32 d_out
    gemm_out<<<dim3(500, 2), blk, 0, stream>>>(outmid, Wout, bout, (float*)d_out);
}